// Round 6
// baseline (728.246 us; speedup 1.0000x reference)
//
#include <hip/hip_runtime.h>

#define NTAGS 128
#define BB    256
#define SS    512

typedef float f32x2 __attribute__((ext_vector_type(2)));

__device__ __forceinline__ float rdlane(float v, int lane) {
    return __int_as_float(__builtin_amdgcn_readlane(__float_as_int(v), lane));
}
__device__ __forceinline__ int fexp_of(float x) {   // exponent of positive normal f32
    return (int)((__float_as_uint(x) >> 23) & 0xFFu) - 127;
}

__global__ void zero_out_kernel(float* out) { out[0] = 0.0f; }

__global__ __launch_bounds__(64, 1) void crf_fwd_kernel(
    const float* __restrict__ emissions,        // [B, S, NTAGS] f32
    const int* __restrict__ tags,               // [B, S] int32
    const unsigned char* __restrict__ mask,     // [B, S] bool
    const float* __restrict__ trans,            // [NTAGS, NTAGS] f32
    float* __restrict__ out)                    // [1] f32
{
    const int b = blockIdx.x;
    const int l = threadIdx.x;                  // 0..63; owns cols l and l+64

    const float* emB = emissions + (size_t)b * SS * NTAGS;

    // ---- setup phase: gold score entirely off the recursion ----
    float gold = 0.0f;
    for (int t = l; t < SS; t += 64) {
        int tg   = tags[b * SS + t];
        float mk = mask[b * SS + t] ? 1.0f : 0.0f;
        gold += emB[(size_t)t * NTAGS + tg] * mk;
        if (t > 0) gold += trans[tags[b * SS + t - 1] * NTAGS + tg] * mk;
    }

    // ---- expT: all 128 rows for the 2 owned columns, packed over columns ----
    f32x2 eTlo[64], eThi[64];                   // 256 regs -> AGPR half of file
    #pragma unroll
    for (int r = 0; r < 64; r++) {
        f32x2 vlo, vhi;
        vlo.x = __expf(trans[(size_t)r * NTAGS + l]);
        vlo.y = __expf(trans[(size_t)r * NTAGS + l + 64]);
        vhi.x = __expf(trans[(size_t)(r + 64) * NTAGS + l]);
        vhi.y = __expf(trans[(size_t)(r + 64) * NTAGS + l + 64]);
        eTlo[r] = vlo; eThi[r] = vhi;
    }

    // ---- init: true alpha_c = p̂_c * 2^S * e^M0 ----
    float a0 = emB[l], a1 = emB[l + 64];
    float M0;
    {
        float v = fmaxf(a0, a1);
        #pragma unroll
        for (int o = 32; o > 0; o >>= 1) v = fmaxf(v, __shfl_xor(v, o));
        M0 = v;
    }
    f32x2 p2;
    p2.x = __expf(a0 - M0);
    p2.y = __expf(a1 - M0);
    int S = 0;
    int exn_prev = max(fexp_of(p2.x), fexp_of(p2.y));
    int K;
    {
        int kv = exn_prev;
        #pragma unroll
        for (int o = 32; o > 0; o >>= 1) kv = max(kv, __shfl_xor(kv, o));
        K = kv;
    }

    // ---- emission pipeline: raw loads 4 steps deep, exp 2 steps off-chain ----
    f32x2 rawO, rawE, infO, infE, exO, exE;
    rawO.x = emB[(size_t)1 * NTAGS + l]; rawO.y = emB[(size_t)1 * NTAGS + l + 64];
    rawE.x = emB[(size_t)2 * NTAGS + l]; rawE.y = emB[(size_t)2 * NTAGS + l + 64];
    infO.x = emB[(size_t)3 * NTAGS + l]; infO.y = emB[(size_t)3 * NTAGS + l + 64];
    infE.x = emB[(size_t)4 * NTAGS + l]; infE.y = emB[(size_t)4 * NTAGS + l + 64];
    exO.x = __expf(rawO.x); exO.y = __expf(rawO.y);
    exE.x = __expf(rawE.x); exE.y = __expf(rawE.y);

    auto step = [&](int t, f32x2& raw_inf, f32x2& ex_cur) {
        // off-chain: next rescale exponent from 1-step-stale p̂ exponents
        int kv = exn_prev;
        #pragma unroll
        for (int o = 32; o > 0; o >>= 1) kv = max(kv, __shfl_xor(kv, o));

        // matvec: 128 readlane + 128 pk_fma, 4 rotating accumulators
        f32x2 acc0 = {0.f,0.f}, acc1 = {0.f,0.f}, acc2 = {0.f,0.f}, acc3 = {0.f,0.f};
        #pragma unroll
        for (int r = 0; r < 64; r += 4) {
            float q0 = rdlane(p2.x, r + 0);
            float q1 = rdlane(p2.x, r + 1);
            float q2 = rdlane(p2.x, r + 2);
            float q3 = rdlane(p2.x, r + 3);
            f32x2 b0 = {q0, q0}, b1 = {q1, q1}, b2 = {q2, q2}, b3 = {q3, q3};
            acc0 = __builtin_elementwise_fma(b0, eTlo[r + 0], acc0);
            acc1 = __builtin_elementwise_fma(b1, eTlo[r + 1], acc1);
            acc2 = __builtin_elementwise_fma(b2, eTlo[r + 2], acc2);
            acc3 = __builtin_elementwise_fma(b3, eTlo[r + 3], acc3);
        }
        #pragma unroll
        for (int r = 0; r < 64; r += 4) {
            float q0 = rdlane(p2.y, r + 0);
            float q1 = rdlane(p2.y, r + 1);
            float q2 = rdlane(p2.y, r + 2);
            float q3 = rdlane(p2.y, r + 3);
            f32x2 b0 = {q0, q0}, b1 = {q1, q1}, b2 = {q2, q2}, b3 = {q3, q3};
            acc0 = __builtin_elementwise_fma(b0, eThi[r + 0], acc0);
            acc1 = __builtin_elementwise_fma(b1, eThi[r + 1], acc1);
            acc2 = __builtin_elementwise_fma(b2, eThi[r + 2], acc2);
            acc3 = __builtin_elementwise_fma(b3, eThi[r + 3], acc3);
        }
        f32x2 sn2 = ((acc0 + acc1) + (acc2 + acc3)) * ex_cur;

        p2.x = ldexpf(sn2.x, -K);
        p2.y = ldexpf(sn2.y, -K);
        S += K;
        exn_prev = max(fexp_of(sn2.x), fexp_of(sn2.y)) - K;
        K = kv;

        // rotate pipeline: load for t+4, exp for t+2 (both off-chain)
        f32x2 nr = raw_inf;
        int tn = t + 4; if (tn > SS - 1) tn = SS - 1;
        raw_inf.x = emB[(size_t)tn * NTAGS + l];
        raw_inf.y = emB[(size_t)tn * NTAGS + l + 64];
        ex_cur.x = __expf(nr.x);
        ex_cur.y = __expf(nr.y);
    };

    for (int t = 1; t < SS; t += 2) {
        step(t, infO, exO);
        if (t + 1 < SS) step(t + 1, infE, exE);
    }

    // ---- epilogue: partition = M0 + S*ln2 + log(sum p̂); reduce gold ----
    {
        float g = gold;
        #pragma unroll
        for (int o = 32; o > 0; o >>= 1) g += __shfl_xor(g, o);

        float sw = p2.x + p2.y;
        #pragma unroll
        for (int o = 32; o > 0; o >>= 1) sw += __shfl_xor(sw, o);

        if (l == 0) {
            float part = M0 + (float)S * 0.69314718055994531f + __logf(sw);
            atomicAdd(out, part - g);
        }
    }
}

extern "C" void kernel_launch(void* const* d_in, const int* in_sizes, int n_in,
                              void* d_out, int out_size, void* d_ws, size_t ws_size,
                              hipStream_t stream) {
    const float*         emissions = (const float*)d_in[0];
    const int*           tags      = (const int*)d_in[1];
    const unsigned char* mask      = (const unsigned char*)d_in[2];
    const float*         trans     = (const float*)d_in[3];
    float*               out       = (float*)d_out;

    zero_out_kernel<<<1, 1, 0, stream>>>(out);
    crf_fwd_kernel<<<BB, 64, 0, stream>>>(emissions, tags, mask, trans, out);
}

// Round 7
// 414.340 us; speedup vs baseline: 1.7576x; 1.7576x over previous
//
#include <hip/hip_runtime.h>

#define NTAGS 128
#define BB    256
#define SS    512

typedef float f32x2 __attribute__((ext_vector_type(2)));

__device__ __forceinline__ float rdlane(float v, int lane) {
    return __int_as_float(__builtin_amdgcn_readlane(__float_as_int(v), lane));
}
__device__ __forceinline__ int fexp_of(float x) {   // exponent of positive normal f32
    return (int)((__float_as_uint(x) >> 23) & 0xFFu) - 127;
}
// barrier draining only LDS ops — global prefetches stay in flight
__device__ __forceinline__ void lds_barrier() {
    asm volatile("s_waitcnt lgkmcnt(0)\n\ts_barrier" ::: "memory");
}

__global__ void zero_out_kernel(float* out) { out[0] = 0.0f; }

__global__ __launch_bounds__(128, 2) void crf_fwd_kernel(
    const float* __restrict__ emissions,        // [B, S, NTAGS] f32
    const int* __restrict__ tags,               // [B, S] int32
    const unsigned char* __restrict__ mask,     // [B, S] bool
    const float* __restrict__ trans,            // [NTAGS, NTAGS] f32
    float* __restrict__ out)                    // [1] f32
{
    const int b   = blockIdx.x;
    const int tid = threadIdx.x;                // 0..127
    const int l   = tid & 63;
    const int w   = tid >> 6;                   // wave 0/1: owns rows 64w..64w+63
    const int jO  = (w << 6) + l;               // owned state/column
    const int jX  = ((1 - w) << 6) + l;         // other wave's column

    __shared__ float pbuf[2][NTAGS];            // parity partial exchange
    __shared__ int   sbuf[2][2];                // parity per-wave scale S
    __shared__ float redf[8];
    __shared__ int   redi[2];

    const float*         emB = emissions + (size_t)b * SS * NTAGS;
    const int*           tgB = tags + b * SS;
    const unsigned char* mkB = mask + b * SS;

    // ---- gold score fully hoisted off the recursion ----
    float gold = 0.0f;
    for (int t = tid; t < SS; t += 128) {
        int tg   = tgB[t];
        float mk = mkB[t] ? 1.0f : 0.0f;
        float a  = emB[(size_t)t * NTAGS + tg];
        if (t > 0) a += trans[tgB[t - 1] * NTAGS + tg];
        gold += a * mk;
    }

    // ---- expT: own 64 rows, columns {jO, jX} packed -> 128 VGPRs ----
    f32x2 eTr[64];
    #pragma unroll
    for (int r = 0; r < 64; r++) {
        const float* row = trans + (size_t)((w << 6) + r) * NTAGS;
        f32x2 v; v.x = __expf(row[jO]); v.y = __expf(row[jX]);
        eTr[r] = v;
    }

    // ---- init: true alpha_j = p̂ * 2^{S_w} * e^{M0} ----
    float a0 = emB[jO];
    {
        float v = a0;
        #pragma unroll
        for (int o = 32; o > 0; o >>= 1) v = fmaxf(v, __shfl_xor(v, o));
        if (l == 0) redf[w] = v;
    }
    __syncthreads();
    const float M0 = fmaxf(redf[0], redf[1]);

    float p = __expf(a0 - M0);
    int S_own = 0;
    int exn_prev = fexp_of(p);
    int K;
    {
        int kv = exn_prev;
        #pragma unroll
        for (int o = 32; o > 0; o >>= 1) kv = max(kv, __shfl_xor(kv, o));
        K = kv;
    }

    // ---- emission pipeline: loads 4 deep, exp 2 steps off-chain ----
    float rawO = emB[(size_t)1 * NTAGS + jO];
    float rawE = emB[(size_t)2 * NTAGS + jO];
    float infO = emB[(size_t)3 * NTAGS + jO];
    float infE = emB[(size_t)4 * NTAGS + jO];
    float exO  = __expf(rawO);                  // exp(e_1)
    float exE  = __expf(rawE);                  // exp(e_2)

    auto step = [&](int t, int q, float& raw_inf, float& ex_cur) {
        // off-chain: next rescale exponent from 1-step-stale p̂ exponents
        int kv = exn_prev;
        #pragma unroll
        for (int o = 32; o > 0; o >>= 1) kv = max(kv, __shfl_xor(kv, o));

        // row-split matvec: 64 readlane + 64 pk_fma over own rows, 2 cols
        f32x2 acc0 = {0.f,0.f}, acc1 = {0.f,0.f}, acc2 = {0.f,0.f}, acc3 = {0.f,0.f};
        #pragma unroll
        for (int r = 0; r < 64; r += 4) {
            float q0 = rdlane(p, r + 0);
            float q1 = rdlane(p, r + 1);
            float q2 = rdlane(p, r + 2);
            float q3 = rdlane(p, r + 3);
            f32x2 b0 = {q0, q0}, b1 = {q1, q1}, b2 = {q2, q2}, b3 = {q3, q3};
            acc0 = __builtin_elementwise_fma(b0, eTr[r + 0], acc0);
            acc1 = __builtin_elementwise_fma(b1, eTr[r + 1], acc1);
            acc2 = __builtin_elementwise_fma(b2, eTr[r + 2], acc2);
            acc3 = __builtin_elementwise_fma(b3, eTr[r + 3], acc3);
        }
        f32x2 s2 = (acc0 + acc1) + (acc2 + acc3);   // {partial jO, partial jX}

        pbuf[q][jX] = s2.y;                     // hand other wave its partial
        if (l == 0) sbuf[q][w] = S_own;
        lds_barrier();                          // lgkm-only: vmcnt untouched
        float sOth  = pbuf[q][jO];
        int   S_oth = sbuf[q][1 - w];

        float sn = (s2.x + ldexpf(sOth, S_oth - S_own)) * ex_cur;

        p = ldexpf(sn, -K);                     // exact power-of-2 rescale
        S_own += K;
        exn_prev = fexp_of(sn) - K;
        K = kv;

        // rotate pipeline: load for t+4, exp for t+2 (off-chain)
        float nr = raw_inf;
        int tn = t + 4; if (tn > SS - 1) tn = SS - 1;
        raw_inf = emB[(size_t)tn * NTAGS + jO];
        ex_cur  = __expf(nr);
    };

    for (int t = 1; t < SS; t += 2) {
        step(t, 1, infO, exO);
        if (t + 1 < SS) step(t + 1, 0, infE, exE);
    }

    // ---- epilogue ----
    {
        float g = gold;
        #pragma unroll
        for (int o = 32; o > 0; o >>= 1) g += __shfl_xor(g, o);
        float sw = p;
        #pragma unroll
        for (int o = 32; o > 0; o >>= 1) sw += __shfl_xor(sw, o);
        if (l == 0) { redf[w] = sw; redf[2 + w] = g; redi[w] = S_own; }
    }
    __syncthreads();
    if (tid == 0) {
        int SA = redi[0], SB = redi[1];
        int Sm = (SA > SB) ? SA : SB;
        float tot  = ldexpf(redf[0], SA - Sm) + ldexpf(redf[1], SB - Sm);
        float part = M0 + (float)Sm * 0.69314718055994531f + __logf(tot);
        atomicAdd(out, part - (redf[2] + redf[3]));
    }
}

extern "C" void kernel_launch(void* const* d_in, const int* in_sizes, int n_in,
                              void* d_out, int out_size, void* d_ws, size_t ws_size,
                              hipStream_t stream) {
    const float*         emissions = (const float*)d_in[0];
    const int*           tags      = (const int*)d_in[1];
    const unsigned char* mask      = (const unsigned char*)d_in[2];
    const float*         trans     = (const float*)d_in[3];
    float*               out       = (float*)d_out;

    zero_out_kernel<<<1, 1, 0, stream>>>(out);
    crf_fwd_kernel<<<BB, 128, 0, stream>>>(emissions, tags, mask, trans, out);
}

// Round 8
// 294.384 us; speedup vs baseline: 2.4738x; 1.4075x over previous
//
#include <hip/hip_runtime.h>

#define NTAGS 128
#define BB    256
#define SS    512

typedef float f32x2 __attribute__((ext_vector_type(2)));

__device__ __forceinline__ float rdlane(float v, int lane) {
    return __int_as_float(__builtin_amdgcn_readlane(__float_as_int(v), lane));
}
__device__ __forceinline__ int fexp_of(float x) {   // exponent of positive normal f32
    return (int)((__float_as_uint(x) >> 23) & 0xFFu) - 127;
}
// barrier draining only LDS ops — global prefetches stay in flight
__device__ __forceinline__ void lds_barrier() {
    asm volatile("s_waitcnt lgkmcnt(0)\n\ts_barrier" ::: "memory");
}

__global__ void zero_out_kernel(float* out) { out[0] = 0.0f; }

__global__ __launch_bounds__(128, 2) void crf_fwd_kernel(
    const float* __restrict__ emissions,        // [B, S, NTAGS] f32
    const int* __restrict__ tags,               // [B, S] int32
    const unsigned char* __restrict__ mask,     // [B, S] bool
    const float* __restrict__ trans,            // [NTAGS, NTAGS] f32
    float* __restrict__ out)                    // [1] f32
{
    const int b   = blockIdx.x;
    const int tid = threadIdx.x;                // 0..127
    const int l   = tid & 63;
    const int w   = tid >> 6;                   // wave 0/1: owns rows 64w..64w+63
    const int jO  = (w << 6) + l;               // owned state/column
    const int jX  = ((1 - w) << 6) + l;         // other wave's column

    __shared__ float pbuf[2][NTAGS];            // parity partial exchange
    __shared__ int   kbuf[2];                   // per-wave K proposal (1x/group)
    __shared__ float redf[8];
    __shared__ int   redi[4];

    const float*         emB = emissions + (size_t)b * SS * NTAGS;
    const int*           tgB = tags + b * SS;
    const unsigned char* mkB = mask + b * SS;

    // ---- gold score fully hoisted off the recursion ----
    float gold = 0.0f;
    for (int t = tid; t < SS; t += 128) {
        int tg   = tgB[t];
        float mk = mkB[t] ? 1.0f : 0.0f;
        float a  = emB[(size_t)t * NTAGS + tg];
        if (t > 0) a += trans[tgB[t - 1] * NTAGS + tg];
        gold += a * mk;
    }

    // ---- expT: own 64 rows, columns {jO, jX} packed -> 128 regs (AGPR ok) ----
    f32x2 eTr[64];
    #pragma unroll
    for (int r = 0; r < 64; r++) {
        const float* row = trans + (size_t)((w << 6) + r) * NTAGS;
        f32x2 v; v.x = __expf(row[jO]); v.y = __expf(row[jX]);
        eTr[r] = v;
    }

    // ---- init: true alpha_j = p̂ * 2^S * e^{M0}, S global ----
    float a0 = emB[jO];
    {
        float v = a0;
        #pragma unroll
        for (int o = 32; o > 0; o >>= 1) v = fmaxf(v, __shfl_xor(v, o));
        if (l == 0) redf[w] = v;
    }
    __syncthreads();
    const float M0 = fmaxf(redf[0], redf[1]);

    float p = __expf(a0 - M0);                  // p̂ ∈ (0,1]
    int S = 0;
    int K = 0;                                  // applied at next group boundary

    // ---- emission pipeline: loads 4 deep, exp 2 steps off-chain ----
    float rawO = emB[(size_t)1 * NTAGS + jO];
    float rawE = emB[(size_t)2 * NTAGS + jO];
    float infO = emB[(size_t)3 * NTAGS + jO];
    float infE = emB[(size_t)4 * NTAGS + jO];
    float exO  = __expf(rawO);                  // exp(e_1)
    float exE  = __expf(rawE);                  // exp(e_2)

    // core: matvec + partial exchange; returns combined sum (pre-emission)
    auto matvec_xchg = [&](int q) -> float {
        f32x2 acc0 = {0.f,0.f}, acc1 = {0.f,0.f}, acc2 = {0.f,0.f}, acc3 = {0.f,0.f};
        #pragma unroll
        for (int r = 0; r < 64; r += 4) {
            float q0 = rdlane(p, r + 0);
            float q1 = rdlane(p, r + 1);
            float q2 = rdlane(p, r + 2);
            float q3 = rdlane(p, r + 3);
            f32x2 b0 = {q0, q0}, b1 = {q1, q1}, b2 = {q2, q2}, b3 = {q3, q3};
            acc0 = __builtin_elementwise_fma(b0, eTr[r + 0], acc0);
            acc1 = __builtin_elementwise_fma(b1, eTr[r + 1], acc1);
            acc2 = __builtin_elementwise_fma(b2, eTr[r + 2], acc2);
            acc3 = __builtin_elementwise_fma(b3, eTr[r + 3], acc3);
        }
        f32x2 s2 = (acc0 + acc1) + (acc2 + acc3);   // {partial jO, partial jX}
        pbuf[q][jX] = s2.y;
        lds_barrier();                               // lgkm-only drain
        return s2.x + pbuf[q][jO];
    };

    auto rot_pipe = [&](int t, float& raw_inf, float& ex_cur) {
        float nr = raw_inf;
        int tn = t + 4; if (tn > SS - 1) tn = SS - 1;
        raw_inf = emB[(size_t)tn * NTAGS + jO];
        ex_cur  = __expf(nr);
    };

    int kv_own = 0;
    // ---- forward recursion: groups of 4 steps; rescale only at sub-step 0 ----
    for (int t = 1; t < SS; t += 4) {
        // ---- sub-step 0 (t, q=1): apply K, then propose next K ----
        {
            float sn = matvec_xchg(1) * exO;
            p = ldexpf(sn, -K);                 // group-boundary rescale (exact)
            S += K;
            // propose next K from post-rescale p (swizzle chain runs 1x/group)
            int kv = fexp_of(p);
            #pragma unroll
            for (int o = 32; o > 0; o >>= 1) kv = max(kv, __shfl_xor(kv, o));
            kv_own = kv;
            rot_pipe(t, infO, exO);
        }
        // ---- sub-step 1 (t+1, q=0): plain + K exchange piggyback ----
        if (t + 1 < SS) {
            if (l == 0) kbuf[w] = kv_own;       // rides the existing barrier
            float sn = matvec_xchg(0) * exE;
            K = max(kv_own, kbuf[1 - w]);       // joint K for next boundary
            p = sn;
            rot_pipe(t + 1, infE, exE);
        }
        // ---- sub-step 2 (t+2, q=1): plain ----
        if (t + 2 < SS) {
            p = matvec_xchg(1) * exO;
            rot_pipe(t + 2, infO, exO);
        }
        // ---- sub-step 3 (t+3, q=0): plain ----
        if (t + 3 < SS) {
            p = matvec_xchg(0) * exE;
            rot_pipe(t + 3, infE, exE);
        }
    }

    // ---- epilogue: partition = M0 + S*ln2 + log(sum p̂); reduce gold ----
    {
        float g = gold;
        #pragma unroll
        for (int o = 32; o > 0; o >>= 1) g += __shfl_xor(g, o);
        float sw = p;
        #pragma unroll
        for (int o = 32; o > 0; o >>= 1) sw += __shfl_xor(sw, o);
        if (l == 0) { redf[w] = sw; redf[2 + w] = g; redi[w] = S; }
    }
    __syncthreads();
    if (tid == 0) {
        // S is global (identical across waves); sums share the same scale
        float tot  = redf[0] + redf[1];
        float part = M0 + (float)redi[0] * 0.69314718055994531f + __logf(tot);
        atomicAdd(out, part - (redf[2] + redf[3]));
    }
}

extern "C" void kernel_launch(void* const* d_in, const int* in_sizes, int n_in,
                              void* d_out, int out_size, void* d_ws, size_t ws_size,
                              hipStream_t stream) {
    const float*         emissions = (const float*)d_in[0];
    const int*           tags      = (const int*)d_in[1];
    const unsigned char* mask      = (const unsigned char*)d_in[2];
    const float*         trans     = (const float*)d_in[3];
    float*               out       = (float*)d_out;

    zero_out_kernel<<<1, 1, 0, stream>>>(out);
    crf_fwd_kernel<<<BB, 128, 0, stream>>>(emissions, tags, mask, trans, out);
}